// Round 3
// baseline (61.676 us; speedup 1.0000x reference)
//
#include <hip/hip_runtime.h>
#include <hip/hip_bf16.h>

// Problem: B=24, L=512, D=64, H=64
//   h = gelu(x @ W + b)                        [24,512,64]
//   S = einsum('ilh,jmh->ijlm', h, h)          [24,24,512,512]
//   scores = logsumexp(S, axis=(2,3))          [24,24]  (TAU=1)
//
// scores = log(sum 2^(S*log2e)); one operand pre-scaled by log2e so the
// MFMA output feeds v_exp_f32 (=2^x) directly. 300 unique (i<=j) pairs.
// No max-shift needed: S <= ~30 -> sum < 2.6e18 < f32 max; sum > 0.
//
// R3: latency-bound fix. 4800 blocks = 300 pairs x (4 row-quarters x 4
// col-chunks of 128). Wave = 32 rows x 128 cols, B double-buffered in
// registers. 19200 waves (4x R2), 2 B/elem L2 traffic, B chunk per block
// = 16KB so sibling waves hit L1. No memset / no atomics: per-wave
// partials to unique slots, reduced in finish_kernel.

#define LOG2E 1.4426950408889634f

typedef unsigned short u16;
typedef __attribute__((ext_vector_type(8))) short bf16x8;
typedef __attribute__((ext_vector_type(4))) float f32x4;

// ---------------- encoder: h = gelu(x@W+b), write bf16 h and h*log2e ------
__global__ __launch_bounds__(256) void encode_kernel(
    const float* __restrict__ x, const float* __restrict__ W,
    const float* __restrict__ bias, u16* __restrict__ hb,
    u16* __restrict__ hlb) {
  int lane = threadIdx.x & 63;
  int row = blockIdx.x * 4 + (threadIdx.x >> 6);   // 12288 rows total
  float xv = x[row * 64 + lane];
  float acc = bias[lane];
#pragma unroll
  for (int d = 0; d < 64; ++d) {
    float xs = __shfl(xv, d, 64);
    acc = fmaf(xs, W[d * 64 + lane], acc);
  }
  // JAX default gelu (approximate=True, tanh form)
  float z = acc;
  float t = tanhf(0.7978845608028654f * (z + 0.044715f * z * z * z));
  float g = 0.5f * z * (1.0f + t);
  __hip_bfloat16 hg = __float2bfloat16(g);
  __hip_bfloat16 hgl = __float2bfloat16(g * LOG2E);
  hb[row * 64 + lane] = *reinterpret_cast<u16*>(&hg);
  hlb[row * 64 + lane] = *reinterpret_cast<u16*>(&hgl);
}

// ---------------- pair kernel ---------------------------------------------
// Block = 256 thr (4 waves), covers 128 rows x 128 cols of one pair's S.
// Wave owns 32 rows (2 rm frags in regs), sweeps 8 x 16-col B fragments
// with register double-buffering. MFMA 16x16x32 bf16 -> v_exp_f32 -> sum.
__global__ __launch_bounds__(256) void pair_kernel(
    const u16* __restrict__ hb, const u16* __restrict__ hlb,
    float* __restrict__ part) {
  int idx = blockIdx.x;
  int p = idx >> 4;
  int tile = idx & 15;
  int quarter = tile >> 2;     // row quarter (128 rows)
  int chunk = tile & 3;        // col chunk (128 cols)
  // decode triangular index p -> (i,j), i<=j
  int i = 0, rem = p;
  while (rem >= 24 - i) { rem -= 24 - i; ++i; }
  int j = i + rem;

  const u16* Ap = hb + (size_t)i * 512 * 64;
  const u16* Bp = hlb + (size_t)j * 512 * 64;

  int wid = threadIdx.x >> 6;
  int lane = threadIdx.x & 63;
  int r = lane & 15;        // row-in-fragment
  int kg = lane >> 4;       // k-group (8 contiguous bf16)
  int row0 = quarter * 128 + wid * 32;
  int col0 = chunk * 128;

  // A fragments: 32 rows, K=64 (2 k-halves)
  bf16x8 a[2][2];
#pragma unroll
  for (int rm = 0; rm < 2; ++rm)
#pragma unroll
    for (int kf = 0; kf < 2; ++kf)
      a[rm][kf] = *reinterpret_cast<const bf16x8*>(
          Ap + (size_t)(row0 + rm * 16 + r) * 64 + kf * 32 + kg * 8);

  const u16* bbase = Bp + (size_t)(col0 + r) * 64 + kg * 8;
  // prime double buffer (cn = 0)
  bf16x8 b0c = *reinterpret_cast<const bf16x8*>(bbase);
  bf16x8 b1c = *reinterpret_cast<const bf16x8*>(bbase + 32);

  float s0 = 0.f, s1 = 0.f, s2 = 0.f, s3 = 0.f;
  const f32x4 zero = {0.f, 0.f, 0.f, 0.f};

#pragma unroll
  for (int cn = 0; cn < 8; ++cn) {
    bf16x8 b0n, b1n;
    if (cn < 7) {  // static (full unroll): prefetch next 16-col fragment
      const u16* bn = bbase + (size_t)(cn + 1) * 16 * 64;
      b0n = *reinterpret_cast<const bf16x8*>(bn);
      b1n = *reinterpret_cast<const bf16x8*>(bn + 32);
    }
#pragma unroll
    for (int rm = 0; rm < 2; ++rm) {
      f32x4 acc = __builtin_amdgcn_mfma_f32_16x16x32_bf16(a[rm][0], b0c, zero, 0, 0, 0);
      acc = __builtin_amdgcn_mfma_f32_16x16x32_bf16(a[rm][1], b1c, acc, 0, 0, 0);
      float e0, e1, e2, e3;
      asm("v_exp_f32 %0, %1" : "=v"(e0) : "v"(acc[0]));
      asm("v_exp_f32 %0, %1" : "=v"(e1) : "v"(acc[1]));
      asm("v_exp_f32 %0, %1" : "=v"(e2) : "v"(acc[2]));
      asm("v_exp_f32 %0, %1" : "=v"(e3) : "v"(acc[3]));
      s0 += e0; s1 += e1; s2 += e2; s3 += e3;
    }
    b0c = b0n; b1c = b1n;
  }
  float sum = (s0 + s1) + (s2 + s3);
#pragma unroll
  for (int off = 32; off >= 1; off >>= 1) sum += __shfl_xor(sum, off, 64);
  if (lane == 0) part[idx * 4 + wid] = sum;
}

// ---------------- finalize: sum 64 partials per pair, log, mirror ---------
__global__ void finish_kernel(const float* __restrict__ part,
                              float* __restrict__ out) {
  int t = threadIdx.x + blockIdx.x * blockDim.x;
  if (t >= 576) return;
  int i = t / 24, j = t % 24;
  int ii = i < j ? i : j, jj = i < j ? j : i;
  int p = ii * 24 - ii * (ii - 1) / 2 + (jj - ii);
  const f32x4* pv = reinterpret_cast<const f32x4*>(part + p * 64);
  float s = 0.f;
#pragma unroll
  for (int q = 0; q < 16; ++q) {
    f32x4 v = pv[q];
    s += (v[0] + v[1]) + (v[2] + v[3]);
  }
  out[t] = logf(s);
}

extern "C" void kernel_launch(void* const* d_in, const int* in_sizes, int n_in,
                              void* d_out, int out_size, void* d_ws,
                              size_t ws_size, hipStream_t stream) {
  const float* x = (const float*)d_in[0];
  const float* W = (const float*)d_in[1];
  const float* bias = (const float*)d_in[2];
  float* out = (float*)d_out;

  u16* hb = (u16*)d_ws;                      // 12288*64 bf16 = 1.50 MiB
  u16* hlb = hb + 12288 * 64;                // 1.50 MiB
  float* part = (float*)(hlb + 12288 * 64);  // 4800 blocks * 4 waves = 19200 f32

  encode_kernel<<<3072, 256, 0, stream>>>(x, W, bias, hb, hlb);
  pair_kernel<<<4800, 256, 0, stream>>>(hb, hlb, part);
  finish_kernel<<<9, 64, 0, stream>>>(part, out);
}

// Round 4
// 34.228 us; speedup vs baseline: 1.8019x; 1.8019x over previous
//
#include <hip/hip_runtime.h>
#include <hip/hip_bf16.h>

// Problem: B=24, L=512, D=64, H=64
//   h = gelu(x @ W + b); S = h_i h_j^T per pair; scores = logsumexp(S).
// scores = log(sum 2^(S*log2e)); B operand pre-scaled by log2e so MFMA
// output feeds v_exp_f32 (=2^x) directly. 300 unique (i<=j) pairs.
//
// R4: latency fix. Same tiling as R3 (4800 blocks = pair x 4 row-quarters
// x 4 col-chunks of 128; wave = 32 rows x 128 cols) but the B chunk
// (16KB) is staged in LDS once via global_load_lds(16B) and consumed by
// ds_read_b128. Row stride 128B = 32 banks -> XOR swizzle
// byte ^= ((row&7)<<4), applied as pre-swizzled GLOBAL SOURCE (gload_lds
// dest must stay linear) + swizzled LDS read. 16KB LDS -> 8 blocks/CU.

#define LOG2E 1.4426950408889634f

typedef unsigned short u16;
typedef __attribute__((ext_vector_type(8))) short bf16x8;
typedef __attribute__((ext_vector_type(4))) float f32x4;

// ---------------- encoder: h = gelu(x@W+b), write bf16 h and h*log2e ------
__global__ __launch_bounds__(256) void encode_kernel(
    const float* __restrict__ x, const float* __restrict__ W,
    const float* __restrict__ bias, u16* __restrict__ hb,
    u16* __restrict__ hlb) {
  int lane = threadIdx.x & 63;
  int row = blockIdx.x * 4 + (threadIdx.x >> 6);   // 12288 rows total
  float xv = x[row * 64 + lane];
  float acc = bias[lane];
#pragma unroll
  for (int d = 0; d < 64; ++d) {
    float xs = __shfl(xv, d, 64);
    acc = fmaf(xs, W[d * 64 + lane], acc);
  }
  // JAX default gelu (approximate=True, tanh form)
  float z = acc;
  float t = tanhf(0.7978845608028654f * (z + 0.044715f * z * z * z));
  float g = 0.5f * z * (1.0f + t);
  __hip_bfloat16 hg = __float2bfloat16(g);
  __hip_bfloat16 hgl = __float2bfloat16(g * LOG2E);
  hb[row * 64 + lane] = *reinterpret_cast<u16*>(&hg);
  hlb[row * 64 + lane] = *reinterpret_cast<u16*>(&hgl);
}

// ---------------- pair kernel ---------------------------------------------
// Block = 256 thr (4 waves) = 128 rows x 128 cols of one pair's S.
// B chunk (128 rows x 64 H = 16KB bf16) staged to LDS, XOR-swizzled.
__global__ __launch_bounds__(256) void pair_kernel(
    const u16* __restrict__ hb, const u16* __restrict__ hlb,
    float* __restrict__ part) {
  __shared__ char smem[16384];

  int idx = blockIdx.x;
  int p = idx >> 4;
  int tile = idx & 15;
  int quarter = tile >> 2;     // row quarter (128 rows of A)
  int chunk = tile & 3;        // col chunk (128 rows of B)
  // decode triangular index p -> (i,j), i<=j
  int i = 0, rem = p;
  while (rem >= 24 - i) { rem -= 24 - i; ++i; }
  int j = i + rem;

  const u16* Ap = hb + (size_t)i * 512 * 64;
  const char* Bbytes =
      (const char*)(hlb + (size_t)j * 512 * 64) + (size_t)chunk * 128 * 128;

  int wid = threadIdx.x >> 6;
  int lane = threadIdx.x & 63;
  int r = lane & 15;        // row-in-fragment
  int kg = lane >> 4;       // k-group (8 contiguous bf16 = 16B)
  int row0 = quarter * 128 + wid * 32;

  // A fragments: 32 rows, K=64 (2 k-halves) — one-time global (L2) loads.
  bf16x8 a[2][2];
#pragma unroll
  for (int rm = 0; rm < 2; ++rm)
#pragma unroll
    for (int kf = 0; kf < 2; ++kf)
      a[rm][kf] = *reinterpret_cast<const bf16x8*>(
          Ap + (size_t)(row0 + rm * 16 + r) * 64 + kf * 32 + kg * 8);

  // Stage B chunk: 16KB = 4 waves x 4 calls x 1KB. LDS dest linear;
  // global source pre-swizzled with the same involution the reads use.
#pragma unroll
  for (int c = 0; c < 4; ++c) {
    int obase = (wid * 4 + c) * 1024;
    int o = obase + lane * 16;
    int src = o ^ (((o >> 7) & 7) << 4);
    __builtin_amdgcn_global_load_lds(
        (const __attribute__((address_space(1))) void*)(Bbytes + src),
        (__attribute__((address_space(3))) void*)(smem + obase), 16, 0, 0);
  }
  __syncthreads();

  float s0 = 0.f, s1 = 0.f, s2 = 0.f, s3 = 0.f;
  const f32x4 zero = {0.f, 0.f, 0.f, 0.f};

#pragma unroll
  for (int cn = 0; cn < 8; ++cn) {
    int rr = cn * 16 + r;
    int base = rr * 128;
    int sw = (rr & 7) << 4;
    bf16x8 b0 = *reinterpret_cast<const bf16x8*>(smem + base + ((kg * 16) ^ sw));
    bf16x8 b1 =
        *reinterpret_cast<const bf16x8*>(smem + base + ((64 + kg * 16) ^ sw));
#pragma unroll
    for (int rm = 0; rm < 2; ++rm) {
      f32x4 acc = __builtin_amdgcn_mfma_f32_16x16x32_bf16(a[rm][0], b0, zero, 0, 0, 0);
      acc = __builtin_amdgcn_mfma_f32_16x16x32_bf16(a[rm][1], b1, acc, 0, 0, 0);
      float e0, e1, e2, e3;
      asm("v_exp_f32 %0, %1" : "=v"(e0) : "v"(acc[0]));
      asm("v_exp_f32 %0, %1" : "=v"(e1) : "v"(acc[1]));
      asm("v_exp_f32 %0, %1" : "=v"(e2) : "v"(acc[2]));
      asm("v_exp_f32 %0, %1" : "=v"(e3) : "v"(acc[3]));
      s0 += e0; s1 += e1; s2 += e2; s3 += e3;
    }
  }
  float sum = (s0 + s1) + (s2 + s3);
#pragma unroll
  for (int off = 32; off >= 1; off >>= 1) sum += __shfl_xor(sum, off, 64);
  if (lane == 0) part[idx * 4 + wid] = sum;
}

// ---------------- finalize: sum 64 partials per pair, log, mirror ---------
__global__ void finish_kernel(const float* __restrict__ part,
                              float* __restrict__ out) {
  int t = threadIdx.x + blockIdx.x * blockDim.x;
  if (t >= 576) return;
  int i = t / 24, j = t % 24;
  int ii = i < j ? i : j, jj = i < j ? j : i;
  int p = ii * 24 - ii * (ii - 1) / 2 + (jj - ii);
  const f32x4* pv = reinterpret_cast<const f32x4*>(part + p * 64);
  float s = 0.f;
#pragma unroll
  for (int q = 0; q < 16; ++q) {
    f32x4 v = pv[q];
    s += (v[0] + v[1]) + (v[2] + v[3]);
  }
  out[t] = logf(s);
}

extern "C" void kernel_launch(void* const* d_in, const int* in_sizes, int n_in,
                              void* d_out, int out_size, void* d_ws,
                              size_t ws_size, hipStream_t stream) {
  const float* x = (const float*)d_in[0];
  const float* W = (const float*)d_in[1];
  const float* bias = (const float*)d_in[2];
  float* out = (float*)d_out;

  u16* hb = (u16*)d_ws;                      // 12288*64 bf16 = 1.50 MiB
  u16* hlb = hb + 12288 * 64;                // 1.50 MiB
  float* part = (float*)(hlb + 12288 * 64);  // 4800 * 4 = 19200 f32

  encode_kernel<<<3072, 256, 0, stream>>>(x, W, bias, hb, hlb);
  pair_kernel<<<4800, 256, 0, stream>>>(hb, hlb, part);
  finish_kernel<<<9, 64, 0, stream>>>(part, out);
}

// Round 6
// 33.861 us; speedup vs baseline: 1.8214x; 1.0108x over previous
//
#include <hip/hip_runtime.h>
#include <hip/hip_bf16.h>

// Problem: B=24, L=512, D=64, H=64
//   h = gelu(x @ W + b); S = h_i h_j^T per pair; scores = logsumexp(S).
// scores = log(sum 2^(S*log2e)); B operand pre-scaled by log2e so MFMA
// output feeds v_exp_f32 (=2^x) directly. 300 unique (i<=j) pairs.
//
// R6: same structure as R5 (wave = 64 rows x 128 cols, 2400 blocks,
// LDS-staged swizzled B) but exp via __builtin_amdgcn_exp2f instead of
// inline asm (hazard-modeled: R5's inf was consistent with a TRANS/MFMA
// hazard through the asm black box), and no launch_bounds reg cap.

#define LOG2E 1.4426950408889634f

typedef unsigned short u16;
typedef __attribute__((ext_vector_type(8))) short bf16x8;
typedef __attribute__((ext_vector_type(4))) float f32x4;

// ---------------- encoder: h = gelu(x@W+b), write bf16 h and h*log2e ------
// 2 rows per wave (independent shfl-fma chains), shared W loads.
__global__ __launch_bounds__(256) void encode_kernel(
    const float* __restrict__ x, const float* __restrict__ W,
    const float* __restrict__ bias, u16* __restrict__ hb,
    u16* __restrict__ hlb) {
  int lane = threadIdx.x & 63;
  int wid = threadIdx.x >> 6;
  int row = blockIdx.x * 8 + wid * 2;          // 12288 rows total
  float xv0 = x[row * 64 + lane];
  float xv1 = x[(row + 1) * 64 + lane];
  float acc0 = bias[lane], acc1 = acc0;
#pragma unroll
  for (int d = 0; d < 64; ++d) {
    float w = W[d * 64 + lane];
    acc0 = fmaf(__shfl(xv0, d, 64), w, acc0);
    acc1 = fmaf(__shfl(xv1, d, 64), w, acc1);
  }
  // JAX default gelu (approximate=True, tanh form)
#pragma unroll
  for (int q = 0; q < 2; ++q) {
    float z = q ? acc1 : acc0;
    float t = tanhf(0.7978845608028654f * (z + 0.044715f * z * z * z));
    float g = 0.5f * z * (1.0f + t);
    __hip_bfloat16 hg = __float2bfloat16(g);
    __hip_bfloat16 hgl = __float2bfloat16(g * LOG2E);
    hb[(row + q) * 64 + lane] = *reinterpret_cast<u16*>(&hg);
    hlb[(row + q) * 64 + lane] = *reinterpret_cast<u16*>(&hgl);
  }
}

// ---------------- pair kernel ---------------------------------------------
// Block = 256 thr (4 waves) = 256 rows x 128 cols of one pair's S.
// Wave = 64 rows (a[4][2] frags in regs) x 128 cols from LDS.
__global__ __launch_bounds__(256) void pair_kernel(
    const u16* __restrict__ hb, const u16* __restrict__ hlb,
    float* __restrict__ part) {
  __shared__ char smem[16384];

  int idx = blockIdx.x;
  int p = idx >> 3;
  int tile = idx & 7;
  int rh = tile >> 2;          // row half (256 rows of A)
  int ch = tile & 3;           // col chunk (128 rows of B)
  // decode triangular index p -> (i,j), i<=j
  int i = 0, rem = p;
  while (rem >= 24 - i) { rem -= 24 - i; ++i; }
  int j = i + rem;

  const u16* Ap = hb + (size_t)i * 512 * 64;
  const char* Bbytes =
      (const char*)(hlb + (size_t)j * 512 * 64) + (size_t)ch * 128 * 128;

  int wid = threadIdx.x >> 6;
  int lane = threadIdx.x & 63;
  int r = lane & 15;        // row-in-fragment
  int kg = lane >> 4;       // k-group (8 contiguous bf16 = 16B)
  int row0 = rh * 256 + wid * 64;

  // A fragments: 64 rows, K=64 (4 rm x 2 k-halves) — one-time L2 loads.
  bf16x8 a[4][2];
#pragma unroll
  for (int rm = 0; rm < 4; ++rm)
#pragma unroll
    for (int kf = 0; kf < 2; ++kf)
      a[rm][kf] = *reinterpret_cast<const bf16x8*>(
          Ap + (size_t)(row0 + rm * 16 + r) * 64 + kf * 32 + kg * 8);

  // Stage B chunk: 16KB = 4 waves x 4 calls x 1KB. LDS dest linear;
  // global source pre-swizzled with the involution the reads use.
#pragma unroll
  for (int c = 0; c < 4; ++c) {
    int obase = (wid * 4 + c) * 1024;
    int o = obase + lane * 16;
    int src = o ^ (((o >> 7) & 7) << 4);
    __builtin_amdgcn_global_load_lds(
        (const __attribute__((address_space(1))) void*)(Bbytes + src),
        (__attribute__((address_space(3))) void*)(smem + obase), 16, 0, 0);
  }

  // Per-lane LDS read offsets (swizzle bits depend only on lane).
  int sw = (r & 7) << 4;
  int off0 = r * 128 + ((kg * 16) ^ sw);
  int off1 = r * 128 + ((64 + kg * 16) ^ sw);

  __syncthreads();

  float s0 = 0.f, s1 = 0.f, s2 = 0.f, s3 = 0.f;
  const f32x4 zero = {0.f, 0.f, 0.f, 0.f};

#pragma unroll
  for (int cn = 0; cn < 8; ++cn) {
    const char* bp = smem + cn * 2048;
    bf16x8 b0 = *reinterpret_cast<const bf16x8*>(bp + off0);
    bf16x8 b1 = *reinterpret_cast<const bf16x8*>(bp + off1);
#pragma unroll
    for (int rm = 0; rm < 4; ++rm) {
      f32x4 acc = __builtin_amdgcn_mfma_f32_16x16x32_bf16(a[rm][0], b0, zero, 0, 0, 0);
      acc = __builtin_amdgcn_mfma_f32_16x16x32_bf16(a[rm][1], b1, acc, 0, 0, 0);
      s0 += __builtin_amdgcn_exp2f(acc[0]);
      s1 += __builtin_amdgcn_exp2f(acc[1]);
      s2 += __builtin_amdgcn_exp2f(acc[2]);
      s3 += __builtin_amdgcn_exp2f(acc[3]);
    }
  }
  float sum = (s0 + s1) + (s2 + s3);
#pragma unroll
  for (int off = 32; off >= 1; off >>= 1) sum += __shfl_xor(sum, off, 64);
  if (lane == 0) part[idx * 4 + wid] = sum;
}

// ---------------- finalize: sum 32 partials per pair, log, mirror ---------
__global__ void finish_kernel(const float* __restrict__ part,
                              float* __restrict__ out) {
  int t = threadIdx.x + blockIdx.x * blockDim.x;
  if (t >= 576) return;
  int i = t / 24, j = t % 24;
  int ii = i < j ? i : j, jj = i < j ? j : i;
  int p = ii * 24 - ii * (ii - 1) / 2 + (jj - ii);
  const f32x4* pv = reinterpret_cast<const f32x4*>(part + p * 32);
  float s = 0.f;
#pragma unroll
  for (int q = 0; q < 8; ++q) {
    f32x4 v = pv[q];
    s += (v[0] + v[1]) + (v[2] + v[3]);
  }
  out[t] = logf(s);
}

extern "C" void kernel_launch(void* const* d_in, const int* in_sizes, int n_in,
                              void* d_out, int out_size, void* d_ws,
                              size_t ws_size, hipStream_t stream) {
  const float* x = (const float*)d_in[0];
  const float* W = (const float*)d_in[1];
  const float* bias = (const float*)d_in[2];
  float* out = (float*)d_out;

  u16* hb = (u16*)d_ws;                      // 12288*64 bf16 = 1.50 MiB
  u16* hlb = hb + 12288 * 64;                // 1.50 MiB
  float* part = (float*)(hlb + 12288 * 64);  // 2400 * 4 = 9600 f32

  encode_kernel<<<1536, 256, 0, stream>>>(x, W, bias, hb, hlb);
  pair_kernel<<<2400, 256, 0, stream>>>(hb, hlb, part);
  finish_kernel<<<9, 64, 0, stream>>>(part, out);
}

// Round 7
// 28.716 us; speedup vs baseline: 2.1478x; 1.1792x over previous
//
#include <hip/hip_runtime.h>
#include <hip/hip_bf16.h>

// Problem: B=24, L=512, D=64, H=64
//   h = gelu(x @ W + b); S = h_i h_j^T per pair; scores = logsumexp(S).
// scores = log(sum 2^(S*log2e)); B operand pre-scaled by log2e so MFMA
// output feeds v_exp_f32 (=2^x) directly. 300 unique (i<=j) pairs.
//
// R7: (1) MFMA encoder (bf16 x@W, K=64) replaces the shfl-broadcast loop
// (encode was ~7-9us of DS-pipe bpermutes). (2) Pair block = 256x256
// (1200 blocks, 32KB LDS staged ONCE, 16 cn per wave) — halves barrier/
// stage overhead per unit compute vs R6. Swizzle + exp2f builtin as R6.

#define LOG2E 1.4426950408889634f

typedef unsigned short u16;
typedef __attribute__((ext_vector_type(8))) short bf16x8;
typedef __attribute__((ext_vector_type(4))) float f32x4;

static __device__ __forceinline__ u16 bf16bits(float f) {
  __hip_bfloat16 h = __float2bfloat16(f);
  return *reinterpret_cast<u16*>(&h);
}

// ---------------- encoder: h = gelu(x@W+b) via MFMA -----------------------
// Wave handles 16 rows. A = x rows (bf16), B = W (bf16). 8 MFMA/wave.
// D layout: col = lane&15, row_in_tile = (lane>>4)*4 + q.
__global__ __launch_bounds__(256) void encode_kernel(
    const float* __restrict__ x, const float* __restrict__ W,
    const float* __restrict__ bias, u16* __restrict__ hb,
    u16* __restrict__ hlb) {
  int lane = threadIdx.x & 63;
  int wid = threadIdx.x >> 6;
  int row0 = (blockIdx.x * 4 + wid) * 16;      // 12288 rows / 16 = 768 waves
  int r = lane & 15;
  int kg = lane >> 4;

  // A fragments: x[row0 + r][kh*32 + kg*8 + e], f32 -> bf16
  bf16x8 xa[2];
#pragma unroll
  for (int kh = 0; kh < 2; ++kh) {
    const float* xp = x + (size_t)(row0 + r) * 64 + kh * 32 + kg * 8;
    bf16x8 v;
#pragma unroll
    for (int e = 0; e < 8; ++e) v[e] = (short)bf16bits(xp[e]);
    xa[kh] = v;
  }

  // B fragments: W[k][c]; lane holds B[k=kh*32+kg*8+e][c=nb*16+r]
  bf16x8 wf[4][2];
#pragma unroll
  for (int nb = 0; nb < 4; ++nb)
#pragma unroll
    for (int kh = 0; kh < 2; ++kh) {
      bf16x8 v;
#pragma unroll
      for (int e = 0; e < 8; ++e)
        v[e] = (short)bf16bits(W[(kh * 32 + kg * 8 + e) * 64 + nb * 16 + r]);
      wf[nb][kh] = v;
    }

  const f32x4 zero = {0.f, 0.f, 0.f, 0.f};
#pragma unroll
  for (int nb = 0; nb < 4; ++nb) {
    f32x4 acc = __builtin_amdgcn_mfma_f32_16x16x32_bf16(xa[0], wf[nb][0], zero, 0, 0, 0);
    acc = __builtin_amdgcn_mfma_f32_16x16x32_bf16(xa[1], wf[nb][1], acc, 0, 0, 0);
    float bb = bias[nb * 16 + r];
#pragma unroll
    for (int q = 0; q < 4; ++q) {
      float z = acc[q] + bb;
      // JAX default gelu (approximate=True, tanh form)
      float t = tanhf(0.7978845608028654f * (z + 0.044715f * z * z * z));
      float g = 0.5f * z * (1.0f + t);
      size_t o = (size_t)(row0 + kg * 4 + q) * 64 + nb * 16 + r;
      hb[o] = bf16bits(g);
      hlb[o] = bf16bits(g * LOG2E);
    }
  }
}

// ---------------- pair kernel ---------------------------------------------
// 1200 blocks = 300 pairs x (2 row-halves x 2 col-halves). Block =
// 256 A-rows x 256 B-rows. B half (256x64 bf16 = 32KB) staged once to
// LDS (XOR-swizzled). Wave = 64 A-rows (a[4][2] regs) x 256 cols (16 cn).
__global__ __launch_bounds__(256) void pair_kernel(
    const u16* __restrict__ hb, const u16* __restrict__ hlb,
    float* __restrict__ part) {
  __shared__ char smem[32768];

  int idx = blockIdx.x;
  int p = idx >> 2;
  int tile = idx & 3;
  int rh = tile >> 1;          // row half of A (256 rows)
  int ch = tile & 1;           // col half of B (256 rows)
  // decode triangular index p -> (i,j), i<=j
  int i = 0, rem = p;
  while (rem >= 24 - i) { rem -= 24 - i; ++i; }
  int j = i + rem;

  const u16* Ap = hb + (size_t)i * 512 * 64;
  const char* Bbytes =
      (const char*)(hlb + (size_t)j * 512 * 64) + (size_t)ch * 256 * 128;

  int wid = threadIdx.x >> 6;
  int lane = threadIdx.x & 63;
  int r = lane & 15;        // row-in-fragment
  int kg = lane >> 4;       // k-group (8 contiguous bf16 = 16B)
  int row0 = rh * 256 + wid * 64;

  // A fragments: 64 rows, K=64 (4 rm x 2 k-halves) — one-time L2 loads.
  bf16x8 a[4][2];
#pragma unroll
  for (int rm = 0; rm < 4; ++rm)
#pragma unroll
    for (int kf = 0; kf < 2; ++kf)
      a[rm][kf] = *reinterpret_cast<const bf16x8*>(
          Ap + (size_t)(row0 + rm * 16 + r) * 64 + kf * 32 + kg * 8);

  // Stage B half: 32KB = 4 waves x 8 calls x 1KB. LDS dest linear;
  // global source pre-swizzled with the involution the reads use.
#pragma unroll
  for (int c = 0; c < 8; ++c) {
    int obase = (wid * 8 + c) * 1024;
    int o = obase + lane * 16;
    int src = o ^ (((o >> 7) & 7) << 4);
    __builtin_amdgcn_global_load_lds(
        (const __attribute__((address_space(1))) void*)(Bbytes + src),
        (__attribute__((address_space(3))) void*)(smem + obase), 16, 0, 0);
  }

  // Per-lane LDS read offsets (swizzle bits depend only on lane).
  int sw = (r & 7) << 4;
  int off0 = r * 128 + ((kg * 16) ^ sw);
  int off1 = r * 128 + ((64 + kg * 16) ^ sw);

  __syncthreads();

  float s0 = 0.f, s1 = 0.f, s2 = 0.f, s3 = 0.f;
  const f32x4 zero = {0.f, 0.f, 0.f, 0.f};

#pragma unroll
  for (int cn = 0; cn < 16; ++cn) {
    const char* bp = smem + cn * 2048;
    bf16x8 b0 = *reinterpret_cast<const bf16x8*>(bp + off0);
    bf16x8 b1 = *reinterpret_cast<const bf16x8*>(bp + off1);
#pragma unroll
    for (int rm = 0; rm < 4; ++rm) {
      f32x4 acc = __builtin_amdgcn_mfma_f32_16x16x32_bf16(a[rm][0], b0, zero, 0, 0, 0);
      acc = __builtin_amdgcn_mfma_f32_16x16x32_bf16(a[rm][1], b1, acc, 0, 0, 0);
      s0 += __builtin_amdgcn_exp2f(acc[0]);
      s1 += __builtin_amdgcn_exp2f(acc[1]);
      s2 += __builtin_amdgcn_exp2f(acc[2]);
      s3 += __builtin_amdgcn_exp2f(acc[3]);
    }
  }
  float sum = (s0 + s1) + (s2 + s3);
#pragma unroll
  for (int off = 32; off >= 1; off >>= 1) sum += __shfl_xor(sum, off, 64);
  if (lane == 0) part[idx * 4 + wid] = sum;
}

// ---------------- finalize: sum 16 partials per pair, log, mirror ---------
__global__ void finish_kernel(const float* __restrict__ part,
                              float* __restrict__ out) {
  int t = threadIdx.x + blockIdx.x * blockDim.x;
  if (t >= 576) return;
  int i = t / 24, j = t % 24;
  int ii = i < j ? i : j, jj = i < j ? j : i;
  int p = ii * 24 - ii * (ii - 1) / 2 + (jj - ii);
  const f32x4* pv = reinterpret_cast<const f32x4*>(part + p * 16);
  float s = 0.f;
#pragma unroll
  for (int q = 0; q < 4; ++q) {
    f32x4 v = pv[q];
    s += (v[0] + v[1]) + (v[2] + v[3]);
  }
  out[t] = logf(s);
}

extern "C" void kernel_launch(void* const* d_in, const int* in_sizes, int n_in,
                              void* d_out, int out_size, void* d_ws,
                              size_t ws_size, hipStream_t stream) {
  const float* x = (const float*)d_in[0];
  const float* W = (const float*)d_in[1];
  const float* bias = (const float*)d_in[2];
  float* out = (float*)d_out;

  u16* hb = (u16*)d_ws;                      // 12288*64 bf16 = 1.50 MiB
  u16* hlb = hb + 12288 * 64;                // 1.50 MiB
  float* part = (float*)(hlb + 12288 * 64);  // 1200 * 4 = 4800 f32

  encode_kernel<<<192, 256, 0, stream>>>(x, W, bias, hb, hlb);
  pair_kernel<<<1200, 256, 0, stream>>>(hb, hlb, part);
  finish_kernel<<<9, 64, 0, stream>>>(part, out);
}

// Round 8
// 27.889 us; speedup vs baseline: 2.2114x; 1.0296x over previous
//
#include <hip/hip_runtime.h>
#include <hip/hip_bf16.h>

// Problem: B=24, L=512, D=64, H=64
//   h = gelu(x @ W + b); S = h_i h_j^T per pair; scores = logsumexp(S).
// scores = log(sum 2^(S*log2e)); B operand pre-scaled by log2e. 300
// unique (i<=j) pairs, mirrored at the end.
//
// R8: kill the TRANS pipe. v_exp_f32 (16+ cyc/wave-op + MFMA->TRANS
// hazards) was the invariant ~8.6us VALU-busy floor across R4/R6/R7.
// Replace with Schraudolph: 2^x ~= as_float((int)(x*2^23 + B)),
// B = 127*2^23 - 254615 (max rel err +-3.0% -> <=0.03 on log scores;
// threshold 1.065, current margin 0.8). fma+cvt = 4 cyc plain VALU,
// co-issues with MFMA, no hazards. Structure otherwise = R7.

#define LOG2E 1.4426950408889634f

typedef unsigned short u16;
typedef __attribute__((ext_vector_type(8))) short bf16x8;
typedef __attribute__((ext_vector_type(4))) float f32x4;

static __device__ __forceinline__ u16 bf16bits(float f) {
  __hip_bfloat16 h = __float2bfloat16(f);
  return *reinterpret_cast<u16*>(&h);
}

// Schraudolph fast 2^x: valid for x in (-126, 128), rel err <= 3.04%.
static __device__ __forceinline__ float fast_exp2(float x) {
  int i = (int)fmaf(x, 8388608.0f, 1065098601.0f);
  return __int_as_float(i);
}

// ---------------- encoder: h = gelu(x@W+b) via MFMA -----------------------
// Wave handles 16 rows. A = x rows (bf16), B = W (bf16). 8 MFMA/wave.
// D layout: col = lane&15, row_in_tile = (lane>>4)*4 + q.
__global__ __launch_bounds__(256) void encode_kernel(
    const float* __restrict__ x, const float* __restrict__ W,
    const float* __restrict__ bias, u16* __restrict__ hb,
    u16* __restrict__ hlb) {
  int lane = threadIdx.x & 63;
  int wid = threadIdx.x >> 6;
  int row0 = (blockIdx.x * 4 + wid) * 16;      // 12288 rows / 16 = 768 waves
  int r = lane & 15;
  int kg = lane >> 4;

  // A fragments: x[row0 + r][kh*32 + kg*8 + e], f32 -> bf16
  bf16x8 xa[2];
#pragma unroll
  for (int kh = 0; kh < 2; ++kh) {
    const float* xp = x + (size_t)(row0 + r) * 64 + kh * 32 + kg * 8;
    bf16x8 v;
#pragma unroll
    for (int e = 0; e < 8; ++e) v[e] = (short)bf16bits(xp[e]);
    xa[kh] = v;
  }

  // B fragments: W[k][c]; lane holds B[k=kh*32+kg*8+e][c=nb*16+r]
  bf16x8 wf[4][2];
#pragma unroll
  for (int nb = 0; nb < 4; ++nb)
#pragma unroll
    for (int kh = 0; kh < 2; ++kh) {
      bf16x8 v;
#pragma unroll
      for (int e = 0; e < 8; ++e)
        v[e] = (short)bf16bits(W[(kh * 32 + kg * 8 + e) * 64 + nb * 16 + r]);
      wf[nb][kh] = v;
    }

  const f32x4 zero = {0.f, 0.f, 0.f, 0.f};
#pragma unroll
  for (int nb = 0; nb < 4; ++nb) {
    f32x4 acc = __builtin_amdgcn_mfma_f32_16x16x32_bf16(xa[0], wf[nb][0], zero, 0, 0, 0);
    acc = __builtin_amdgcn_mfma_f32_16x16x32_bf16(xa[1], wf[nb][1], acc, 0, 0, 0);
    float bb = bias[nb * 16 + r];
#pragma unroll
    for (int q = 0; q < 4; ++q) {
      float z = acc[q] + bb;
      // JAX default gelu (approximate=True, tanh form)
      float t = tanhf(0.7978845608028654f * (z + 0.044715f * z * z * z));
      float g = 0.5f * z * (1.0f + t);
      size_t o = (size_t)(row0 + kg * 4 + q) * 64 + nb * 16 + r;
      hb[o] = bf16bits(g);
      hlb[o] = bf16bits(g * LOG2E);
    }
  }
}

// ---------------- pair kernel ---------------------------------------------
// 1200 blocks = 300 pairs x (2 row-halves x 2 col-halves). Block =
// 256 A-rows x 256 B-rows. B half (256x64 bf16 = 32KB) staged once to
// LDS (XOR-swizzled). Wave = 64 A-rows (a[4][2] regs) x 256 cols (16 cn).
__global__ __launch_bounds__(256) void pair_kernel(
    const u16* __restrict__ hb, const u16* __restrict__ hlb,
    float* __restrict__ part) {
  __shared__ char smem[32768];

  int idx = blockIdx.x;
  int p = idx >> 2;
  int tile = idx & 3;
  int rh = tile >> 1;          // row half of A (256 rows)
  int ch = tile & 1;           // col half of B (256 rows)
  // decode triangular index p -> (i,j), i<=j
  int i = 0, rem = p;
  while (rem >= 24 - i) { rem -= 24 - i; ++i; }
  int j = i + rem;

  const u16* Ap = hb + (size_t)i * 512 * 64;
  const char* Bbytes =
      (const char*)(hlb + (size_t)j * 512 * 64) + (size_t)ch * 256 * 128;

  int wid = threadIdx.x >> 6;
  int lane = threadIdx.x & 63;
  int r = lane & 15;        // row-in-fragment
  int kg = lane >> 4;       // k-group (8 contiguous bf16 = 16B)
  int row0 = rh * 256 + wid * 64;

  // A fragments: 64 rows, K=64 (4 rm x 2 k-halves) — one-time L2 loads.
  bf16x8 a[4][2];
#pragma unroll
  for (int rm = 0; rm < 4; ++rm)
#pragma unroll
    for (int kf = 0; kf < 2; ++kf)
      a[rm][kf] = *reinterpret_cast<const bf16x8*>(
          Ap + (size_t)(row0 + rm * 16 + r) * 64 + kf * 32 + kg * 8);

  // Stage B half: 32KB = 4 waves x 8 calls x 1KB. LDS dest linear;
  // global source pre-swizzled with the involution the reads use.
#pragma unroll
  for (int c = 0; c < 8; ++c) {
    int obase = (wid * 8 + c) * 1024;
    int o = obase + lane * 16;
    int src = o ^ (((o >> 7) & 7) << 4);
    __builtin_amdgcn_global_load_lds(
        (const __attribute__((address_space(1))) void*)(Bbytes + src),
        (__attribute__((address_space(3))) void*)(smem + obase), 16, 0, 0);
  }

  // Per-lane LDS read offsets (swizzle bits depend only on lane).
  int sw = (r & 7) << 4;
  int off0 = r * 128 + ((kg * 16) ^ sw);
  int off1 = r * 128 + ((64 + kg * 16) ^ sw);

  __syncthreads();

  float s0 = 0.f, s1 = 0.f, s2 = 0.f, s3 = 0.f;
  const f32x4 zero = {0.f, 0.f, 0.f, 0.f};

#pragma unroll
  for (int cn = 0; cn < 16; ++cn) {
    const char* bp = smem + cn * 2048;
    bf16x8 b0 = *reinterpret_cast<const bf16x8*>(bp + off0);
    bf16x8 b1 = *reinterpret_cast<const bf16x8*>(bp + off1);
#pragma unroll
    for (int rm = 0; rm < 4; ++rm) {
      f32x4 acc = __builtin_amdgcn_mfma_f32_16x16x32_bf16(a[rm][0], b0, zero, 0, 0, 0);
      acc = __builtin_amdgcn_mfma_f32_16x16x32_bf16(a[rm][1], b1, acc, 0, 0, 0);
      s0 += fast_exp2(acc[0]);
      s1 += fast_exp2(acc[1]);
      s2 += fast_exp2(acc[2]);
      s3 += fast_exp2(acc[3]);
    }
  }
  float sum = (s0 + s1) + (s2 + s3);
#pragma unroll
  for (int off = 32; off >= 1; off >>= 1) sum += __shfl_xor(sum, off, 64);
  if (lane == 0) part[idx * 4 + wid] = sum;
}

// ---------------- finalize: sum 16 partials per pair, log, mirror ---------
__global__ void finish_kernel(const float* __restrict__ part,
                              float* __restrict__ out) {
  int t = threadIdx.x + blockIdx.x * blockDim.x;
  if (t >= 576) return;
  int i = t / 24, j = t % 24;
  int ii = i < j ? i : j, jj = i < j ? j : i;
  int p = ii * 24 - ii * (ii - 1) / 2 + (jj - ii);
  const f32x4* pv = reinterpret_cast<const f32x4*>(part + p * 16);
  float s = 0.f;
#pragma unroll
  for (int q = 0; q < 4; ++q) {
    f32x4 v = pv[q];
    s += (v[0] + v[1]) + (v[2] + v[3]);
  }
  out[t] = logf(s);
}

extern "C" void kernel_launch(void* const* d_in, const int* in_sizes, int n_in,
                              void* d_out, int out_size, void* d_ws,
                              size_t ws_size, hipStream_t stream) {
  const float* x = (const float*)d_in[0];
  const float* W = (const float*)d_in[1];
  const float* bias = (const float*)d_in[2];
  float* out = (float*)d_out;

  u16* hb = (u16*)d_ws;                      // 12288*64 bf16 = 1.50 MiB
  u16* hlb = hb + 12288 * 64;                // 1.50 MiB
  float* part = (float*)(hlb + 12288 * 64);  // 1200 * 4 = 4800 f32

  encode_kernel<<<192, 256, 0, stream>>>(x, W, bias, hb, hlb);
  pair_kernel<<<1200, 256, 0, stream>>>(hb, hlb, part);
  finish_kernel<<<9, 64, 0, stream>>>(part, out);
}